// Round 6
// baseline (283.232 us; speedup 1.0000x reference)
//
#include <hip/hip_runtime.h>
#include <hip/hip_bf16.h>
#include <stdint.h>

#define N_DIM 2048
#define BATCH_SZ 8192

typedef __bf16 bf16;
typedef __bf16 bf16x4 __attribute__((ext_vector_type(4)));
typedef __bf16 bf16x8 __attribute__((ext_vector_type(8)));
typedef float f32x4 __attribute__((ext_vector_type(4)));

// Async global->LDS, 16B per lane. LDS dest is wave-uniform base + lane*16.
__device__ __forceinline__ void gld16(const bf16* g, bf16* l) {
  __builtin_amdgcn_global_load_lds(
      (const __attribute__((address_space(1))) void*)g,
      (__attribute__((address_space(3))) void*)l, 16, 0, 0);
}

// Build Wb = bf16(W) where W = -S (so exp(W) = Q^T), Wtb = bf16(W^T) = bf16(S).
__global__ void unfold_kernel(const float* __restrict__ Sflat,
                              bf16* __restrict__ Wb,
                              bf16* __restrict__ Wtb) {
  int idx = blockIdx.x * blockDim.x + threadIdx.x;
  int i = idx >> 11;            // row
  int j = idx & (N_DIM - 1);    // col
  float v = 0.0f;               // v = S[i][j]
  if (i < j) {
    int fi = i * (N_DIM - 1) - ((i * (i - 1)) >> 1) + (j - i - 1);
    v = Sflat[fi];
  } else if (i > j) {
    int fi = j * (N_DIM - 1) - ((j * (j - 1)) >> 1) + (i - j - 1);
    v = -Sflat[fi];
  }
  Wb[idx]  = (bf16)(-v);   // W = -S
  Wtb[idx] = (bf16)(v);    // W^T = S
}

// fp32 -> bf16 elementwise (vectorized x4)
__global__ void cast_kernel(const float* __restrict__ in, bf16* __restrict__ out) {
  int t = blockIdx.x * blockDim.x + threadIdx.x;
  float4 v = ((const float4*)in)[t];
  bf16x4 o;
  o.x = (bf16)v.x; o.y = (bf16)v.y; o.z = (bf16)v.z; o.w = (bf16)v.w;
  ((bf16x4*)out)[t] = o;
}

// ---------------------------------------------------------------------------
// Split-K reduction + epilogue for the weight GEMMs. P holds 4 f32 partial
// 2048x2048 slices (stride 2048^2 = 1<<22 elems). One float4 per thread.
// MODE 1: O1 = bf16(v) [W2];  O2 = bf16(I/2 - W/6 + v/24)  [B^T operand]
// MODE 2: O1 = bf16(v + I + W)                              (Q^T)
template <int MODE>
__global__ __launch_bounds__(256) void reduce_kernel(
    const float* __restrict__ P, const bf16* __restrict__ Wb,
    bf16* __restrict__ O1, bf16* __restrict__ O2) {
  const int t = blockIdx.x * blockDim.x + threadIdx.x;   // float4 index
  const float4 p0 = ((const float4*)P)[t];
  const float4 p1 = ((const float4*)(P + (1u << 22)))[t];
  const float4 p2 = ((const float4*)(P + (2u << 22)))[t];
  const float4 p3 = ((const float4*)(P + (3u << 22)))[t];
  float v[4] = {p0.x + p1.x + p2.x + p3.x, p0.y + p1.y + p2.y + p3.y,
                p0.z + p1.z + p2.z + p3.z, p0.w + p1.w + p2.w + p3.w};
  const int i    = t * 4;
  const int row  = i >> 11;
  const int col0 = i & (N_DIM - 1);
  const bf16x4 wv = ((const bf16x4*)Wb)[t];
  bf16x4 o1, o2;
#pragma unroll
  for (int r = 0; r < 4; ++r) {
    const float w = (float)wv[r];
    const float d = (row == col0 + r) ? 1.0f : 0.0f;
    if (MODE == 1) {
      o1[r] = (bf16)v[r];
      o2[r] = (bf16)(0.5f * d - (1.0f / 6.0f) * w + (1.0f / 24.0f) * v[r]);
    } else {
      o1[r] = (bf16)(v[r] + d + w);
    }
  }
  ((bf16x4*)O1)[t] = o1;
  if (MODE == 1) ((bf16x4*)O2)[t] = o2;
}

// ---------------------------------------------------------------------------
// Pipelined 256x256 GEMM (proven structure, R1/R4: 890 TF on G3).
// C(MxN) f32 = A(MxK_slice) @ Bt(NxK_slice)^T, bf16 in. 8 waves (2Mx4N),
// BK=32, 4-deep LDS ring (128 KiB), global_load_lds staging 3 tiles ahead,
// counted vmcnt (never 0 in steady state), one raw s_barrier per K-tile,
// setprio around the MFMA cluster.
// Split-K: blockIdx.z selects K-slice [z*KS, (z+1)*KS); output partial is
// written to Cf + z*M*N (z=0, KS=K for the non-split G3 case).
// Requires: gridDim.x == 8 (N == 2048... bx = wg&7), KS % 128 == 0, KS/32 >= 4,
// (gridDim.x*gridDim.y) % 8 == 0.
__global__ __launch_bounds__(512, 2) void gemm256(
    const bf16* __restrict__ A, const bf16* __restrict__ Bt,
    float* __restrict__ Cf, int M, int N, int K, int KS) {
  __shared__ __align__(16) bf16 As[4 * 256 * 32];   // 64 KB
  __shared__ __align__(16) bf16 Bs[4 * 256 * 32];   // 64 KB

  const int tid  = threadIdx.x;
  const int lane = tid & 63;
  const int wave = tid >> 6;     // 0..7
  const int wr   = wave >> 2;    // 0..1  M-half
  const int wc   = wave & 3;     // 0..3  N-quarter
  const int quad = lane >> 4;
  const int l16  = lane & 15;

  // Bijective XCD swizzle over the 2D tile grid (nwg divisible by 8).
  const int nwg    = gridDim.x * gridDim.y;
  const int linear = blockIdx.y * gridDim.x + blockIdx.x;
  const int wg = (linear & 7) * (nwg >> 3) + (linear >> 3);
  const int bx = wg & 7;         // gridDim.x == 8
  const int by = wg >> 3;
  const int m0 = by * 256;
  const int n0 = bx * 256;

  // K-slice and partial-output base for split-K.
  const int ks0 = blockIdx.z * KS;
  Cf += (size_t)blockIdx.z * M * N;

  const int srow  = lane >> 2;
  const int sslot = (lane & 3) ^ ((lane >> 3) & 3);
  const bf16* pA1 = A  + (size_t)(m0 + wave * 16 + srow) * K + ks0 + sslot * 8;
  const bf16* pA2 = pA1 + (size_t)128 * K;
  const bf16* pB1 = Bt + (size_t)(n0 + wave * 16 + srow) * K + ks0 + sslot * 8;
  const bf16* pB2 = pB1 + (size_t)128 * K;
  bf16* lA1 = As + wave * 512;          // + buf*8192
  bf16* lA2 = As + wave * 512 + 4096;
  bf16* lB1 = Bs + wave * 512;
  bf16* lB2 = Bs + wave * 512 + 4096;

  const int NT = KS >> 5;   // K-tiles of 32 (multiple of 4)

  // Prologue: stage tiles 0,1,2 into ring buffers 0,1,2 (12 loads/thread),
  // then wait for tile 0 only (8 loads stay in flight).
#pragma unroll
  for (int tt = 0; tt < 3; ++tt) {
    gld16(pA1 + tt * 32, lA1 + tt * 8192);
    gld16(pA2 + tt * 32, lA2 + tt * 8192);
    gld16(pB1 + tt * 32, lB1 + tt * 8192);
    gld16(pB2 + tt * 32, lB2 + tt * 8192);
  }
  asm volatile("s_waitcnt vmcnt(8)" ::: "memory");
  __builtin_amdgcn_s_barrier();
  __builtin_amdgcn_sched_barrier(0);

  f32x4 acc[8][4] = {};
  const int rswz = (quad ^ ((l16 >> 1) & 3)) * 8;  // reader swizzle (elems)
  const int arow = wr * 128 + l16;
  const int brow = wc * 64 + l16;

  size_t kpre = 96;   // element k-offset (within slice) of tile t+3 at t=0

#pragma unroll 1
  for (int t4 = 0; t4 < NT; t4 += 4) {
#pragma unroll
    for (int u = 0; u < 4; ++u) {
      const int t = t4 + u;
      // Issue staging for tile t+3 -> buffer (u+3)&3.
      if (t + 3 < NT) {
        const int b = (u + 3) & 3;
        const size_t ko = kpre + (size_t)u * 32;
        gld16(pA1 + ko, lA1 + b * 8192);
        gld16(pA2 + ko, lA2 + b * 8192);
        gld16(pB1 + ko, lB1 + b * 8192);
        gld16(pB2 + ko, lB2 + b * 8192);
      }
      // Compute tile t from buffer u.
      const bf16* ab = As + u * 8192;
      const bf16* bb = Bs + u * 8192;
      bf16x8 af[8], bfr[4];
#pragma unroll
      for (int mi = 0; mi < 8; ++mi)
        af[mi] = *(const bf16x8*)&ab[(arow + mi * 16) * 32 + rswz];
#pragma unroll
      for (int ni = 0; ni < 4; ++ni)
        bfr[ni] = *(const bf16x8*)&bb[(brow + ni * 16) * 32 + rswz];
      __builtin_amdgcn_s_setprio(1);
#pragma unroll
      for (int mi = 0; mi < 8; ++mi)
#pragma unroll
        for (int ni = 0; ni < 4; ++ni)
          acc[mi][ni] = __builtin_amdgcn_mfma_f32_16x16x32_bf16(
              af[mi], bfr[ni], acc[mi][ni], 0, 0, 0);
      __builtin_amdgcn_s_setprio(0);
      // K-tile boundary: retire tile t+1's 4 loads, keep the rest in flight.
      if (t < NT - 1) {
        if (t < NT - 3)
          asm volatile("s_waitcnt vmcnt(8)" ::: "memory");
        else if (t == NT - 3)
          asm volatile("s_waitcnt vmcnt(4)" ::: "memory");
        else
          asm volatile("s_waitcnt vmcnt(0)" ::: "memory");
        __builtin_amdgcn_sched_barrier(0);
        __builtin_amdgcn_s_barrier();
        __builtin_amdgcn_sched_barrier(0);
      }
    }
    kpre += 128;
  }

  // Epilogue: C/D layout col = lane&15, row = quad*4 + reg.
#pragma unroll
  for (int mi = 0; mi < 8; ++mi) {
    const int r0 = m0 + wr * 128 + mi * 16 + quad * 4;
#pragma unroll
    for (int ni = 0; ni < 4; ++ni) {
      const int col = n0 + wc * 64 + ni * 16 + l16;
#pragma unroll
      for (int r = 0; r < 4; ++r)
        Cf[(size_t)(r0 + r) * N + col] = acc[mi][ni][r];
    }
  }
}

extern "C" void kernel_launch(void* const* d_in, const int* in_sizes, int n_in,
                              void* d_out, int out_size, void* d_ws, size_t ws_size,
                              hipStream_t stream) {
  const float* X     = (const float*)d_in[0];
  const float* Sflat = (const float*)d_in[1];
  float* out = (float*)d_out;
  char* ws = (char*)d_ws;

  // Workspace (72 MB total):
  bf16* Xb   = (bf16*)(ws);                 // 32 MB  bf16(X)
  bf16* Wb   = (bf16*)(ws + (32u << 20));   //  8 MB  bf16(W),   W = -S
  bf16* Wtb  = (bf16*)(ws + (40u << 20));   //  8 MB  bf16(W^T)
  bf16* W2b  = (bf16*)(ws + (48u << 20));   //  8 MB  bf16(W^2)
  bf16* Btm  = (bf16*)(ws + (56u << 20));   //  8 MB  bf16(B^T) operand for G2
  bf16* Qtb  = (bf16*)(ws + (64u << 20));   //  8 MB  bf16(Q^T)

  // Split-K partials scratch: d_out (64 MB) is dead until G3 overwrites it.
  float* P = out;   // 4 slices of 2048^2 f32

  unfold_kernel<<<(N_DIM * N_DIM) / 256, 256, 0, stream>>>(Sflat, Wb, Wtb);
  cast_kernel<<<(BATCH_SZ * N_DIM / 4) / 256, 256, 0, stream>>>(X, Xb);

  // G1: W2 = W @ W (Bt = W^T), split-K 4 -> 256 blocks of the proven
  // gemm256 structure (full machine), partials into d_out scratch.
  gemm256<<<dim3(8, 8, 4), 512, 0, stream>>>(
      Wb, Wtb, P, N_DIM, N_DIM, N_DIM, 512);
  // Reduce + epilogue: W2b = bf16(sum); Btm = bf16(I/2 - W/6 + sum/24).
  reduce_kernel<1><<<(N_DIM * N_DIM / 4) / 256, 256, 0, stream>>>(
      P, Wb, W2b, Btm);

  // G2: Q^T = I + W + W2 @ B (Bt = B^T), same split-K 4.
  gemm256<<<dim3(8, 8, 4), 512, 0, stream>>>(
      W2b, Btm, P, N_DIM, N_DIM, N_DIM, 512);
  // Reduce + epilogue: Qtb = bf16(sum + I + W).
  reduce_kernel<2><<<(N_DIM * N_DIM / 4) / 256, 256, 0, stream>>>(
      P, Wb, Qtb, nullptr);

  // G3: out = X @ Q (Bt = Q^T row-major). 256 blocks, no split (z=1, KS=K).
  gemm256<<<dim3(N_DIM / 256, BATCH_SZ / 256, 1), 512, 0, stream>>>(
      Xb, Qtb, out, BATCH_SZ, N_DIM, N_DIM, N_DIM);
}

// Round 7
// 262.012 us; speedup vs baseline: 1.0810x; 1.0810x over previous
//
#include <hip/hip_runtime.h>
#include <hip/hip_bf16.h>
#include <stdint.h>

#define N_DIM 2048
#define BATCH_SZ 8192

typedef __bf16 bf16;
typedef __bf16 bf16x4 __attribute__((ext_vector_type(4)));
typedef __bf16 bf16x8 __attribute__((ext_vector_type(8)));
typedef float f32x4 __attribute__((ext_vector_type(4)));

// Async global->LDS, 16B per lane. LDS dest is wave-uniform base + lane*16.
__device__ __forceinline__ void gld16(const bf16* g, bf16* l) {
  __builtin_amdgcn_global_load_lds(
      (const __attribute__((address_space(1))) void*)g,
      (__attribute__((address_space(3))) void*)l, 16, 0, 0);
}

// ---------------------------------------------------------------------------
// Tiled unfold: Wb = bf16(-S), Wtb = bf16(S) from the packed strict-upper
// Sflat, WITHOUT the old kernel's per-lane scattered reads (old i>j branch
// read one cache line per element ~ 128 MB effective fetch).
// Each block handles tile-pair (bi,bj), bi <= bj: reads ONLY the upper tile
// coalesced (fi contiguous in j for fixed i), stages in padded LDS, emits
// the mirrored tile via transposed LDS reads. All global reads/writes are
// coalesced rows.
__global__ __launch_bounds__(256) void unfold_t(const float* __restrict__ Sflat,
                                                bf16* __restrict__ Wb,
                                                bf16* __restrict__ Wtb) {
  const int bi = blockIdx.y;   // tile row
  const int bj = blockIdx.x;   // tile col
  if (bi > bj) return;
  __shared__ float U[64][65];  // padded: transposed reads conflict-free
  const int t  = threadIdx.x;
  const int c  = t & 63;
  const int r0 = t >> 6;       // 0..3

#pragma unroll
  for (int k = 0; k < 16; ++k) {
    const int r = k * 4 + r0;
    const int i = bi * 64 + r;
    const int j = bj * 64 + c;
    float v = 0.0f;
    if (i < j) {   // coalesced: fi contiguous in j for fixed i
      const int fi = i * (N_DIM - 1) - ((i * (i - 1)) >> 1) + (j - i - 1);
      v = Sflat[fi];
    }
    U[r][c] = v;
  }
  __syncthreads();

  if (bi == bj) {
    // Full tile from staged upper part: S = U[r][c] - U[c][r]
    // (c>r: U[r][c]; c<r: -U[c][r]; c==r: 0).
#pragma unroll
    for (int k = 0; k < 16; ++k) {
      const int r = k * 4 + r0;
      const float s = U[r][c] - U[c][r];
      const size_t idx = (size_t)(bi * 64 + r) * N_DIM + bj * 64 + c;
      Wb[idx]  = (bf16)(-s);
      Wtb[idx] = (bf16)( s);
    }
  } else {
#pragma unroll
    for (int k = 0; k < 16; ++k) {
      const int r = k * 4 + r0;
      // Direct tile (rows bi, cols bj): S = U[r][c].
      const float u = U[r][c];
      const size_t idx = (size_t)(bi * 64 + r) * N_DIM + bj * 64 + c;
      Wb[idx]  = (bf16)(-u);
      Wtb[idx] = (bf16)( u);
      // Mirror tile (rows bj, cols bi): S[rm][cm] = -U[c][r].
      const float um = U[c][r];   // stride-65 LDS read: conflict-free
      const size_t idm = (size_t)(bj * 64 + r) * N_DIM + bi * 64 + c;
      Wb[idm]  = (bf16)( um);
      Wtb[idm] = (bf16)(-um);
    }
  }
}

// fp32 -> bf16 elementwise (vectorized x4)
__global__ void cast_kernel(const float* __restrict__ in, bf16* __restrict__ out) {
  int t = blockIdx.x * blockDim.x + threadIdx.x;
  float4 v = ((const float4*)in)[t];
  bf16x4 o;
  o.x = (bf16)v.x; o.y = (bf16)v.y; o.z = (bf16)v.z; o.w = (bf16)v.w;
  ((bf16x4*)out)[t] = o;
}

// ---------------------------------------------------------------------------
// Weight GEMM (G1/G2), reverted to R4's measured-best: 64x128 tile ->
// 512 blocks = 2 blocks/CU (2 independent waves/SIMD), K-step 64
// (2 x BK32 sub-buffers), ring-3 (72 KB LDS), prefetch-2, counted vmcnt(6).
// MODE 1: O1 = bf16(acc) [W2];  O2 = bf16(I/2 - W/6 + acc/24) [B^T operand]
// MODE 2: O1 = bf16(acc + I + W)                          (Q^T)
// Requires: M % 64 == 0, N % 128 == 0 (gridDim.x == 16), K % 64 == 0.
template <int MODE>
__global__ __launch_bounds__(256, 2) void gemm_w(
    const bf16* __restrict__ A, const bf16* __restrict__ Bt,
    bf16* __restrict__ O1, bf16* __restrict__ O2,
    const bf16* __restrict__ Wb, int M, int N, int K) {
  __shared__ __align__(16) bf16 As[3 * 2 * 64 * 32];    // 24 KB
  __shared__ __align__(16) bf16 Bs[3 * 2 * 128 * 32];   // 48 KB

  const int tid  = threadIdx.x;
  const int lane = tid & 63;
  const int wave = tid >> 6;     // 0..3
  const int wr   = wave >> 1;    // 0..1  M-half (32 rows)
  const int wc   = wave & 1;     // 0..1  N-half (64 cols)
  const int quad = lane >> 4;
  const int l16  = lane & 15;

  // Bijective XCD swizzle (nwg = 512, divisible by 8).
  const int nwg    = gridDim.x * gridDim.y;
  const int linear = blockIdx.y * gridDim.x + blockIdx.x;
  const int wg = (linear & 7) * (nwg >> 3) + (linear >> 3);
  const int bx = wg & 15;        // gridDim.x == 16
  const int by = wg >> 4;
  const int m0 = by * 64;
  const int n0 = bx * 128;

  const int srow  = lane >> 2;
  const int sslot = (lane & 3) ^ ((lane >> 3) & 3);
  const bf16* gA  = A  + (size_t)(m0 + wave * 16 + srow) * K + sslot * 8;
  const bf16* gB1 = Bt + (size_t)(n0 + wave * 16 + srow) * K + sslot * 8;
  const bf16* gB2 = gB1 + (size_t)64 * K;
  bf16* lA  = As + wave * 512;   // + (s*2+k)*2048
  bf16* lB1 = Bs + wave * 512;   // + (s*2+k)*4096
  bf16* lB2 = Bs + wave * 512 + 2048;

  const int NS = K >> 6;   // K-steps of 64

  auto STAGE = [&](int t, int s) {
#pragma unroll
    for (int k = 0; k < 2; ++k) {
      const size_t ko = (size_t)t * 64 + k * 32;
      gld16(gA  + ko, lA  + (s * 2 + k) * 2048);
      gld16(gB1 + ko, lB1 + (s * 2 + k) * 4096);
      gld16(gB2 + ko, lB2 + (s * 2 + k) * 4096);
    }
  };

  STAGE(0, 0);
  STAGE(1, 1);
  asm volatile("s_waitcnt vmcnt(6)" ::: "memory");
  __builtin_amdgcn_sched_barrier(0);
  __builtin_amdgcn_s_barrier();
  __builtin_amdgcn_sched_barrier(0);

  f32x4 acc[2][4] = {};
  const int rswz = (quad ^ ((l16 >> 1) & 3)) * 8;
  const int arow = wr * 32 + l16;
  const int brow = wc * 64 + l16;

  auto body = [&](int t, int s) {
    if (t + 2 < NS) STAGE(t + 2, (s + 2) % 3);
    bf16x8 af[2][2], bfr[2][4];
#pragma unroll
    for (int k = 0; k < 2; ++k) {
      const bf16* ab = As + (s * 2 + k) * 2048;
      const bf16* bb = Bs + (s * 2 + k) * 4096;
#pragma unroll
      for (int mi = 0; mi < 2; ++mi)
        af[k][mi] = *(const bf16x8*)&ab[(arow + mi * 16) * 32 + rswz];
#pragma unroll
      for (int ni = 0; ni < 4; ++ni)
        bfr[k][ni] = *(const bf16x8*)&bb[(brow + ni * 16) * 32 + rswz];
    }
    __builtin_amdgcn_s_setprio(1);
#pragma unroll
    for (int k = 0; k < 2; ++k)
#pragma unroll
      for (int mi = 0; mi < 2; ++mi)
#pragma unroll
        for (int ni = 0; ni < 4; ++ni)
          acc[mi][ni] = __builtin_amdgcn_mfma_f32_16x16x32_bf16(
              af[k][mi], bfr[k][ni], acc[mi][ni], 0, 0, 0);
    __builtin_amdgcn_s_setprio(0);
    if (t < NS - 1) {
      if (t + 2 < NS)
        asm volatile("s_waitcnt vmcnt(6)" ::: "memory");
      else
        asm volatile("s_waitcnt vmcnt(0)" ::: "memory");
      __builtin_amdgcn_sched_barrier(0);
      __builtin_amdgcn_s_barrier();
      __builtin_amdgcn_sched_barrier(0);
    }
  };

  const int NS3 = NS - (NS % 3);
#pragma unroll 1
  for (int t0 = 0; t0 < NS3; t0 += 3) {
    body(t0, 0);
    body(t0 + 1, 1);
    body(t0 + 2, 2);
  }
#pragma unroll
  for (int u = 0; u < 3; ++u) {
    const int t = NS3 + u;
    if (t < NS) body(t, u);
  }

  // Epilogue. C/D layout: col = lane&15, row = quad*4 + reg.
#pragma unroll
  for (int mi = 0; mi < 2; ++mi) {
    const int r0 = m0 + wr * 32 + mi * 16 + quad * 4;
#pragma unroll
    for (int ni = 0; ni < 4; ++ni) {
      const int col = n0 + wc * 64 + ni * 16 + l16;
#pragma unroll
      for (int r = 0; r < 4; ++r) {
        const int row = r0 + r;
        const size_t idx = (size_t)row * N + col;
        const float v = acc[mi][ni][r];
        if (MODE == 1) {
          O1[idx] = (bf16)v;
          const float w = (float)Wb[idx];
          const float d = (row == col) ? 1.0f : 0.0f;
          O2[idx] = (bf16)(0.5f * d - (1.0f / 6.0f) * w + (1.0f / 24.0f) * v);
        } else {  // MODE 2: Q^T = acc + I + W
          const float w = (float)Wb[idx];
          const float d = (row == col) ? 1.0f : 0.0f;
          O1[idx] = (bf16)(v + d + w);
        }
      }
    }
  }
}

// ---------------------------------------------------------------------------
// G3 kernel (frozen at round-1 version: best measured, 77 us, ~890 TF).
// C(MxN) f32 = A(MxK) @ Bt(NxK)^T, bf16 in. 256x256 tile, 8 waves (2Mx4N),
// BK=32, 4-deep LDS ring (128 KiB), global_load_lds staging 3 tiles ahead,
// counted vmcnt (never 0 in steady state), one raw s_barrier per K-tile,
// setprio around the MFMA cluster.
// Requires: N == gridDim.x*256 with gridDim.x == 8, K % 128 == 0, K/32 >= 4.
__global__ __launch_bounds__(512, 2) void gemm256(
    const bf16* __restrict__ A, const bf16* __restrict__ Bt,
    float* __restrict__ Cf, int M, int N, int K) {
  __shared__ __align__(16) bf16 As[4 * 256 * 32];   // 64 KB
  __shared__ __align__(16) bf16 Bs[4 * 256 * 32];   // 64 KB

  const int tid  = threadIdx.x;
  const int lane = tid & 63;
  const int wave = tid >> 6;     // 0..7
  const int wr   = wave >> 2;    // 0..1  M-half
  const int wc   = wave & 3;     // 0..3  N-quarter
  const int quad = lane >> 4;
  const int l16  = lane & 15;

  // Bijective XCD swizzle (nwg = 256 divisible by 8).
  const int nwg    = gridDim.x * gridDim.y;
  const int linear = blockIdx.y * gridDim.x + blockIdx.x;
  const int wg = (linear & 7) * (nwg >> 3) + (linear >> 3);
  const int bx = wg & 7;         // gridDim.x == 8 (N == 2048)
  const int by = wg >> 3;
  const int m0 = by * 256;
  const int n0 = bx * 256;

  const int srow  = lane >> 2;
  const int sslot = (lane & 3) ^ ((lane >> 3) & 3);
  const bf16* pA1 = A  + (size_t)(m0 + wave * 16 + srow) * K + sslot * 8;
  const bf16* pA2 = pA1 + (size_t)128 * K;
  const bf16* pB1 = Bt + (size_t)(n0 + wave * 16 + srow) * K + sslot * 8;
  const bf16* pB2 = pB1 + (size_t)128 * K;
  bf16* lA1 = As + wave * 512;          // + buf*8192
  bf16* lA2 = As + wave * 512 + 4096;
  bf16* lB1 = Bs + wave * 512;
  bf16* lB2 = Bs + wave * 512 + 4096;

  const int NT = K >> 5;   // K-tiles of 32

#pragma unroll
  for (int tt = 0; tt < 3; ++tt) {
    gld16(pA1 + tt * 32, lA1 + tt * 8192);
    gld16(pA2 + tt * 32, lA2 + tt * 8192);
    gld16(pB1 + tt * 32, lB1 + tt * 8192);
    gld16(pB2 + tt * 32, lB2 + tt * 8192);
  }
  asm volatile("s_waitcnt vmcnt(8)" ::: "memory");
  __builtin_amdgcn_s_barrier();
  __builtin_amdgcn_sched_barrier(0);

  f32x4 acc[8][4] = {};
  const int rswz = (quad ^ ((l16 >> 1) & 3)) * 8;  // reader swizzle (elems)
  const int arow = wr * 128 + l16;
  const int brow = wc * 64 + l16;

  size_t kpre = 96;   // element k-offset of tile t+3 at t=0

#pragma unroll 1
  for (int t4 = 0; t4 < NT; t4 += 4) {
#pragma unroll
    for (int u = 0; u < 4; ++u) {
      const int t = t4 + u;
      if (t + 3 < NT) {
        const int b = (u + 3) & 3;
        const size_t ko = kpre + (size_t)u * 32;
        gld16(pA1 + ko, lA1 + b * 8192);
        gld16(pA2 + ko, lA2 + b * 8192);
        gld16(pB1 + ko, lB1 + b * 8192);
        gld16(pB2 + ko, lB2 + b * 8192);
      }
      const bf16* ab = As + u * 8192;
      const bf16* bb = Bs + u * 8192;
      bf16x8 af[8], bfr[4];
#pragma unroll
      for (int mi = 0; mi < 8; ++mi)
        af[mi] = *(const bf16x8*)&ab[(arow + mi * 16) * 32 + rswz];
#pragma unroll
      for (int ni = 0; ni < 4; ++ni)
        bfr[ni] = *(const bf16x8*)&bb[(brow + ni * 16) * 32 + rswz];
      __builtin_amdgcn_s_setprio(1);
#pragma unroll
      for (int mi = 0; mi < 8; ++mi)
#pragma unroll
        for (int ni = 0; ni < 4; ++ni)
          acc[mi][ni] = __builtin_amdgcn_mfma_f32_16x16x32_bf16(
              af[mi], bfr[ni], acc[mi][ni], 0, 0, 0);
      __builtin_amdgcn_s_setprio(0);
      if (t < NT - 1) {
        if (t < NT - 3)
          asm volatile("s_waitcnt vmcnt(8)" ::: "memory");
        else if (t == NT - 3)
          asm volatile("s_waitcnt vmcnt(4)" ::: "memory");
        else
          asm volatile("s_waitcnt vmcnt(0)" ::: "memory");
        __builtin_amdgcn_sched_barrier(0);
        __builtin_amdgcn_s_barrier();
        __builtin_amdgcn_sched_barrier(0);
      }
    }
    kpre += 128;
  }

  // Epilogue: C/D layout col = lane&15, row = quad*4 + reg.
#pragma unroll
  for (int mi = 0; mi < 8; ++mi) {
    const int r0 = m0 + wr * 128 + mi * 16 + quad * 4;
#pragma unroll
    for (int ni = 0; ni < 4; ++ni) {
      const int col = n0 + wc * 64 + ni * 16 + l16;
#pragma unroll
      for (int r = 0; r < 4; ++r)
        Cf[(size_t)(r0 + r) * N + col] = acc[mi][ni][r];
    }
  }
}

extern "C" void kernel_launch(void* const* d_in, const int* in_sizes, int n_in,
                              void* d_out, int out_size, void* d_ws, size_t ws_size,
                              hipStream_t stream) {
  const float* X     = (const float*)d_in[0];
  const float* Sflat = (const float*)d_in[1];
  float* out = (float*)d_out;
  char* ws = (char*)d_ws;

  // Workspace (72 MB total):
  bf16* Xb   = (bf16*)(ws);                 // 32 MB  bf16(X)
  bf16* Wb   = (bf16*)(ws + (32u << 20));   //  8 MB  bf16(W),   W = -S
  bf16* Wtb  = (bf16*)(ws + (40u << 20));   //  8 MB  bf16(W^T)
  bf16* W2b  = (bf16*)(ws + (48u << 20));   //  8 MB  bf16(W^2)
  bf16* Btm  = (bf16*)(ws + (56u << 20));   //  8 MB  bf16(B^T) operand for G2
  bf16* Qtb  = (bf16*)(ws + (64u << 20));   //  8 MB  bf16(Q^T)

  // Tiled unfold: coalesced reads/writes via LDS transpose (replaces the
  // scatter-read unfold suspected of ~50-70 us).
  unfold_t<<<dim3(32, 32), 256, 0, stream>>>(Sflat, Wb, Wtb);
  cast_kernel<<<(BATCH_SZ * N_DIM / 4) / 256, 256, 0, stream>>>(X, Xb);

  // Weight GEMMs (R4 measured-best): 64x128 tiles -> 512 blocks = 2/CU.
  const dim3 gW(N_DIM / 128, N_DIM / 64);
  gemm_w<1><<<gW, 256, 0, stream>>>(Wb, Wtb, W2b, Btm, Wb,
                                    N_DIM, N_DIM, N_DIM);
  gemm_w<2><<<gW, 256, 0, stream>>>(W2b, Btm, Qtb, nullptr, Wb,
                                    N_DIM, N_DIM, N_DIM);
  // G3: out = X @ Q (Bt = Q^T row-major). Frozen round-1 kernel.
  gemm256<<<dim3(N_DIM / 256, BATCH_SZ / 256), 512, 0, stream>>>(
      Xb, Qtb, out, BATCH_SZ, N_DIM, N_DIM);
}